// Round 1
// baseline (734.333 us; speedup 1.0000x reference)
//
#include <hip/hip_runtime.h>
#include <hip/hip_bf16.h>

// Problem constants
#define N 8192
#define NEMB 256
#define NHID 64

__device__ __forceinline__ float elu_f(float x) {
    return x > 0.f ? x : __expf(x) - 1.f;
}

__device__ __forceinline__ void fma4(float4& a, float s, const float4& b) {
    a.x = fmaf(s, b.x, a.x);
    a.y = fmaf(s, b.y, a.y);
    a.z = fmaf(s, b.z, a.z);
    a.w = fmaf(s, b.w, a.w);
}

// ---------------------------------------------------------------------------
// K0: h = x @ Ww + Wb  [8192,64]; f_src = h@a1, f_dst = h@a2  [8192]
// Block = 256 threads = 4 rows x 64 cols. One wave per row (lane = k).
// ---------------------------------------------------------------------------
__global__ __launch_bounds__(256) void k0_h_f(
    const float* __restrict__ x, const float* __restrict__ Ww,
    const float* __restrict__ Wb, const float* __restrict__ a1,
    const float* __restrict__ a2, float* __restrict__ h,
    float* __restrict__ fs, float* __restrict__ fd)
{
    __shared__ float xs[4 * NEMB];
    int t = threadIdx.x;
    int rowblk = blockIdx.x * 4;
    // stage 4 rows of x (contiguous 1024 floats)
    for (int i = 0; i < 4; i++)
        xs[i * NEMB + t] = x[(size_t)rowblk * NEMB + i * NEMB + t];
    __syncthreads();
    int rl = t >> 6;     // 0..3 (wave id)
    int k  = t & 63;     // lane = output column
    float acc = Wb[k];
    const float* xrow = &xs[rl * NEMB];
    for (int c = 0; c < NEMB; c++)
        acc = fmaf(xrow[c], Ww[c * NHID + k], acc);
    int row = rowblk + rl;
    h[(size_t)row * NHID + k] = acc;
    // wave reduce (64 lanes, only lanes 0..63 of this wave participate)
    float s1 = acc * a1[k];
    float s2 = acc * a2[k];
    for (int o = 32; o > 0; o >>= 1) {
        s1 += __shfl_down(s1, o, 64);
        s2 += __shfl_down(s2, o, 64);
    }
    if (k == 0) { fs[row] = s1; fd[row] = s2; }
}

// ---------------------------------------------------------------------------
// K1: adj (int32) -> row bitmask (uint64 words, bit b of word w = col w*64+b)
//     + per-row nonzero count.  One block per row, int4 loads.
// ---------------------------------------------------------------------------
__global__ __launch_bounds__(256) void k1_bits(
    const int* __restrict__ adj, unsigned long long* __restrict__ bits,
    unsigned int* __restrict__ cnt)
{
    int row = blockIdx.x;
    int t = threadIdx.x;
    int lane = t & 63;
    const int* arow = adj + (size_t)row * N;
    unsigned long long* brow = bits + (size_t)row * (N / 64);
    __shared__ unsigned int wcs[16];
    unsigned int c = 0;
    for (int it = 0; it < 8; it++) {
        int j = it * 1024 + t * 4;
        int4 a = *(const int4*)&arow[j];
        unsigned int nb = (unsigned)(a.x > 0) | ((unsigned)(a.y > 0) << 1) |
                          ((unsigned)(a.z > 0) << 2) | ((unsigned)(a.w > 0) << 3);
        // assemble 64-bit words across 16 lanes (ordered)
        unsigned int v8  = nb  | (__shfl_down((int)nb, 1, 64) << 4);
        unsigned int v16 = v8  | (__shfl_down((int)v8, 2, 64) << 8);
        unsigned int v32 = v16 | (__shfl_down((int)v16, 4, 64) << 16);
        unsigned int hi  = (unsigned int)__shfl_down((int)v32, 8, 64);
        if ((lane & 15) == 0) {
            unsigned long long word = (unsigned long long)v32 |
                                      ((unsigned long long)hi << 32);
            brow[it * 16 + (t >> 4)] = word;
            c += __popcll(word);
        }
    }
    if ((t & 15) == 0) wcs[t >> 4] = c;
    __syncthreads();
    if (t == 0) {
        unsigned int s = 0;
        for (int i = 0; i < 16; i++) s += wcs[i];
        cnt[row] = s;
    }
}

// ---------------------------------------------------------------------------
// K2: exclusive prefix over cnt[8192] -> rowbase[8192]. One block.
// ---------------------------------------------------------------------------
__global__ __launch_bounds__(256) void k2_scan(
    const unsigned int* __restrict__ cnt, unsigned int* __restrict__ rowbase)
{
    __shared__ unsigned int ts[256];
    int t = threadIdx.x;
    unsigned int loc[32];
    unsigned int s = 0;
    const unsigned int* cp = cnt + t * 32;
    for (int i = 0; i < 32; i++) { loc[i] = s; s += cp[i]; }
    ts[t] = s;
    __syncthreads();
    unsigned int inc = s;
    for (int o = 1; o < 256; o <<= 1) {
        unsigned int u = (t >= o) ? ts[t - o] : 0u;
        __syncthreads();
        inc += u;
        ts[t] = inc;
        __syncthreads();
    }
    unsigned int base = (t == 0) ? 0u : ts[t - 1];
    unsigned int* rp = rowbase + t * 32;
    for (int i = 0; i < 32; i++) rp[i] = base + loc[i];
}

// ---------------------------------------------------------------------------
// K3: per-row softmax stats: m[i] = max v, linv[i] = 1/sum(exp(v-m)).
// Values depend only on RANK r: v = lrelu(fs[r>>13] + fd[r&8191] + ab).
// One block per row.
// ---------------------------------------------------------------------------
__global__ __launch_bounds__(256) void k3_ml(
    const unsigned long long* __restrict__ bits,
    const unsigned int* __restrict__ cnt,
    const unsigned int* __restrict__ rowbase,
    const float* __restrict__ fs, const float* __restrict__ fd,
    const float* __restrict__ ab, float* __restrict__ mrow,
    float* __restrict__ linv)
{
    int row = blockIdx.x;
    int t = threadIdx.x;
    __shared__ unsigned int ps[256];
    __shared__ float red[256];
    unsigned long long w64 = bits[(size_t)row * (N / 64) + (t >> 1)];
    unsigned int w = (t & 1) ? (unsigned int)(w64 >> 32)
                             : (unsigned int)(w64 & 0xffffffffu);
    int pc = __popc(w);
    ps[t] = (unsigned)pc;
    __syncthreads();
    unsigned int inc = (unsigned)pc;
    for (int o = 1; o < 256; o <<= 1) {
        unsigned int u = (t >= o) ? ps[t - o] : 0u;
        __syncthreads();
        inc += u;
        ps[t] = inc;
        __syncthreads();
    }
    unsigned int base = rowbase[row] + inc - (unsigned)pc; // exclusive
    float ab0 = ab[0];
    float mx = -3.0e38f;
    for (int i = 0; i < pc; i++) {
        unsigned int r = base + (unsigned)i;
        float v = fs[r >> 13] + fd[r & 8191] + ab0;
        v = v > 0.f ? v : 0.01f * v;
        mx = fmaxf(mx, v);
    }
    red[t] = mx;
    __syncthreads();
    for (int o = 128; o > 0; o >>= 1) {
        if (t < o) red[t] = fmaxf(red[t], red[t + o]);
        __syncthreads();
    }
    float m = red[0];
    __syncthreads();
    float sm = 0.f;
    for (int i = 0; i < pc; i++) {
        unsigned int r = base + (unsigned)i;
        float v = fs[r >> 13] + fd[r & 8191] + ab0;
        v = v > 0.f ? v : 0.01f * v;
        sm += __expf(v - m);
    }
    red[t] = sm;
    __syncthreads();
    for (int o = 128; o > 0; o >>= 1) {
        if (t < o) red[t] += red[t + o];
        __syncthreads();
    }
    if (t == 0) {
        if (cnt[row] == 0u) { mrow[row] = 0.f; linv[row] = 1.f; }
        else { mrow[row] = m; linv[row] = 1.0f / red[0]; }
    }
}

// ---------------------------------------------------------------------------
// K4: out = elu(P @ h).  256 blocks x 32 rows. Per 512-j chunk:
//   phase A: reconstruct ranks branchlessly, p -> LDS p-tile (swizzled)
//   phase B: fp32 FMA, thread = 2 rows x 4 cols, h staged in LDS.
// ---------------------------------------------------------------------------
#define PROW 548   // ptile row stride (floats): 8*68 + 4  -> uniform bank groups
#define PW   68    // per-64-bit-word stride inside a ptile row

__global__ __launch_bounds__(256, 1) void k4_main(
    const unsigned long long* __restrict__ bits,
    const unsigned int* __restrict__ cnt,
    const unsigned int* __restrict__ rowbase,
    const float* __restrict__ fs, const float* __restrict__ fd,
    const float* __restrict__ ab, const float* __restrict__ mrow,
    const float* __restrict__ linv, const float* __restrict__ h,
    float* __restrict__ out)
{
    __shared__ __align__(16) float ptile[32 * PROW];   // ~68.5 KB
    __shared__ __align__(16) float htile[128 * NHID];  // 32 KB
    __shared__ __align__(16) float fdl[N];             // 32 KB
    __shared__ unsigned int rowcur[32];
    __shared__ float msh[32], lish[32];
    __shared__ int cz[32];

    int t = threadIdx.x;
    int r0 = blockIdx.x * 32;
    // stage fd into LDS
    for (int it = 0; it < 8; it++) {
        int fi = it * 1024 + t * 4;
        *(float4*)&fdl[fi] = *(const float4*)&fd[fi];
    }
    if (t < 32) {
        int row = r0 + t;
        rowcur[t] = rowbase[row];
        msh[t] = mrow[row];
        lish[t] = linv[row];
        cz[t] = (cnt[row] == 0u) ? 1 : 0;
    }
    float4 acc0 = {0.f, 0.f, 0.f, 0.f};
    float4 acc1 = {0.f, 0.f, 0.f, 0.f};
    float ab0 = ab[0];
    int rg = t >> 4, kg = t & 15;   // phase-B mapping
    int rl = t >> 3, w = t & 7;     // phase-A mapping
    int lane = t & 63;

    for (int c = 0; c < 16; c++) {
        __syncthreads();  // ptile free to overwrite; rowcur updates visible
        // ---- phase A: build p-tile for j in [c*512, c*512+512) ----
        unsigned long long w64 = bits[(size_t)(r0 + rl) * (N / 64) + c * 8 + w];
        int pc = __popcll(w64);
        int excl = 0;
        for (int k = 0; k < 8; k++) {
            int pck = __shfl(pc, (lane & ~7) + k, 64);
            if (k < w) excl += pck;
        }
        unsigned int base = rowcur[rl] + (unsigned)excl;
        float mv = msh[rl], lv = lish[rl];
        int zr = cz[rl];
        float* pdst = &ptile[rl * PROW + w * PW];
#pragma unroll 4
        for (int b4 = 0; b4 < 16; b4++) {
            float4 pv;
#pragma unroll
            for (int q = 0; q < 4; q++) {
                int b = b4 * 4 + q;
                unsigned long long below = (1ull << b) - 1ull;  // b==0 -> 0
                unsigned int n = (unsigned)__popcll(w64 & below);
                unsigned int r = base + n;
                float v = fs[r >> 13] + fdl[r & 8191] + ab0;
                v = v > 0.f ? v : 0.01f * v;
                float p = __expf(v - mv) * lv;
                bool set = (w64 >> b) & 1ull;
                p = set ? p : 0.f;
                p = zr ? (1.0f / 8192.0f) : p;
                (&pv.x)[q] = p;
            }
            *(float4*)(pdst + b4 * 4) = pv;
        }
        __syncthreads();
        if (w == 7) rowcur[rl] = base + (unsigned)pc;  // = old + tot
        // ---- phase B: FMA over 4 sub-chunks of 128 j ----
        for (int s = 0; s < 4; s++) {
            if (s) __syncthreads();
            const float* hsrc = h + (size_t)(c * 512 + s * 128) * NHID;
            for (int it = 0; it < 8; it++) {
                int fi = it * 1024 + t * 4;
                *(float4*)&htile[fi] = *(const float4*)&hsrc[fi];
            }
            __syncthreads();
            int jb = s * 128;
            const float* pr0 = &ptile[(2 * rg) * PROW];
            const float* pr1 = &ptile[(2 * rg + 1) * PROW];
#pragma unroll 4
            for (int j = 0; j < 128; j += 4) {
                int jc = jb + j;
                int off = (jc >> 6) * PW + (jc & 63);
                float4 p0 = *(const float4*)(pr0 + off);
                float4 p1 = *(const float4*)(pr1 + off);
                float4 h0 = *(const float4*)&htile[(j + 0) * NHID + kg * 4];
                float4 h1 = *(const float4*)&htile[(j + 1) * NHID + kg * 4];
                float4 h2 = *(const float4*)&htile[(j + 2) * NHID + kg * 4];
                float4 h3 = *(const float4*)&htile[(j + 3) * NHID + kg * 4];
                fma4(acc0, p0.x, h0); fma4(acc0, p0.y, h1);
                fma4(acc0, p0.z, h2); fma4(acc0, p0.w, h3);
                fma4(acc1, p1.x, h0); fma4(acc1, p1.y, h1);
                fma4(acc1, p1.z, h2); fma4(acc1, p1.w, h3);
            }
        }
    }
    // epilogue: elu + store
    int row0 = r0 + 2 * rg;
    float4 o0, o1;
    o0.x = elu_f(acc0.x); o0.y = elu_f(acc0.y);
    o0.z = elu_f(acc0.z); o0.w = elu_f(acc0.w);
    o1.x = elu_f(acc1.x); o1.y = elu_f(acc1.y);
    o1.z = elu_f(acc1.z); o1.w = elu_f(acc1.w);
    *(float4*)&out[(size_t)row0 * NHID + kg * 4] = o0;
    *(float4*)&out[(size_t)(row0 + 1) * NHID + kg * 4] = o1;
}

// ---------------------------------------------------------------------------
extern "C" void kernel_launch(void* const* d_in, const int* in_sizes, int n_in,
                              void* d_out, int out_size, void* d_ws, size_t ws_size,
                              hipStream_t stream)
{
    const float* x  = (const float*)d_in[0];
    const int*   adj = (const int*)d_in[1];
    const float* Ww = (const float*)d_in[2];
    const float* Wb = (const float*)d_in[3];
    const float* a1 = (const float*)d_in[4];
    const float* a2 = (const float*)d_in[5];
    const float* ab = (const float*)d_in[6];
    float* out = (float*)d_out;

    char* ws = (char*)d_ws;
    float* h   = (float*)(ws + 0);                        // 2 MB
    float* fs  = (float*)(ws + 2097152);                  // 32 KB
    float* fd  = (float*)(ws + 2129920);                  // 32 KB
    float* mr  = (float*)(ws + 2162688);                  // 32 KB
    float* li  = (float*)(ws + 2195456);                  // 32 KB
    unsigned int* cnt = (unsigned int*)(ws + 2228224);    // 32 KB
    unsigned int* rb  = (unsigned int*)(ws + 2260992);    // 32 KB
    unsigned long long* bits = (unsigned long long*)(ws + 2293760); // 8 MB

    k0_h_f<<<N / 4, 256, 0, stream>>>(x, Ww, Wb, a1, a2, h, fs, fd);
    k1_bits<<<N, 256, 0, stream>>>(adj, bits, cnt);
    k2_scan<<<1, 256, 0, stream>>>(cnt, rb);
    k3_ml<<<N, 256, 0, stream>>>(bits, cnt, rb, fs, fd, ab, mr, li);
    k4_main<<<256, 256, 0, stream>>>(bits, cnt, rb, fs, fd, ab, mr, li, h, out);
}

// Round 2
// 476.026 us; speedup vs baseline: 1.5426x; 1.5426x over previous
//
#include <hip/hip_runtime.h>
#include <hip/hip_bf16.h>

// Problem constants
#define N 8192
#define NEMB 256
#define NHID 64

typedef __attribute__((ext_vector_type(8))) short short8;   // 8 bf16 (4 VGPRs)
typedef __attribute__((ext_vector_type(4))) float f32x4;    // 4 fp32

__device__ __forceinline__ float elu_f(float x) {
    return x > 0.f ? x : __expf(x) - 1.f;
}

__device__ __forceinline__ short f2bf(float f) {
    union { float f; unsigned u; } c; c.f = f;
    unsigned r = c.u + 0x7fffu + ((c.u >> 16) & 1u);   // RNE
    return (short)(r >> 16);
}

__device__ __forceinline__ float bf2f(short s) {
    union { unsigned u; float f; } c; c.u = ((unsigned)(unsigned short)s) << 16;
    return c.f;
}

// ---------------------------------------------------------------------------
// K0: h = x @ Ww + Wb -> hT (bf16, [64][8192]); fs = h@a1, fd = h@a2.
// Block = 256 threads = 4 rows x 64 cols; one wave per row (lane = col).
// ---------------------------------------------------------------------------
__global__ __launch_bounds__(256) void k0_h_f(
    const float* __restrict__ x, const float* __restrict__ Ww,
    const float* __restrict__ Wb, const float* __restrict__ a1,
    const float* __restrict__ a2, short* __restrict__ hT,
    float* __restrict__ fs, float* __restrict__ fd)
{
    __shared__ float xs[4 * NEMB];
    int t = threadIdx.x;
    int rowblk = blockIdx.x * 4;
    for (int i = 0; i < 4; i++)
        xs[i * NEMB + t] = x[(size_t)rowblk * NEMB + i * NEMB + t];
    __syncthreads();
    int rl = t >> 6;     // 0..3 (wave id = row)
    int k  = t & 63;     // lane = output column
    float acc = Wb[k];
    const float* xrow = &xs[rl * NEMB];
    for (int c = 0; c < NEMB; c++)
        acc = fmaf(xrow[c], Ww[c * NHID + k], acc);
    int row = rowblk + rl;
    hT[(size_t)k * N + row] = f2bf(acc);
    float s1 = acc * a1[k];
    float s2 = acc * a2[k];
    for (int o = 32; o > 0; o >>= 1) {
        s1 += __shfl_down(s1, o, 64);
        s2 += __shfl_down(s2, o, 64);
    }
    if (k == 0) { fs[row] = s1; fd[row] = s2; }
}

// ---------------------------------------------------------------------------
// K1: adj (int32) -> row bitmask (uint64 words) + per-row popcount.
// ---------------------------------------------------------------------------
__global__ __launch_bounds__(256) void k1_bits(
    const int* __restrict__ adj, unsigned long long* __restrict__ bits,
    unsigned int* __restrict__ cnt)
{
    int row = blockIdx.x;
    int t = threadIdx.x;
    int lane = t & 63;
    const int* arow = adj + (size_t)row * N;
    unsigned long long* brow = bits + (size_t)row * (N / 64);
    __shared__ unsigned int wcs[16];
    unsigned int c = 0;
    for (int it = 0; it < 8; it++) {
        int j = it * 1024 + t * 4;
        int4 a = *(const int4*)&arow[j];
        unsigned int nb = (unsigned)(a.x > 0) | ((unsigned)(a.y > 0) << 1) |
                          ((unsigned)(a.z > 0) << 2) | ((unsigned)(a.w > 0) << 3);
        unsigned int v8  = nb  | (__shfl_down((int)nb, 1, 64) << 4);
        unsigned int v16 = v8  | (__shfl_down((int)v8, 2, 64) << 8);
        unsigned int v32 = v16 | (__shfl_down((int)v16, 4, 64) << 16);
        unsigned int hi  = (unsigned int)__shfl_down((int)v32, 8, 64);
        if ((lane & 15) == 0) {
            unsigned long long word = (unsigned long long)v32 |
                                      ((unsigned long long)hi << 32);
            brow[it * 16 + (t >> 4)] = word;
            c += __popcll(word);
        }
    }
    if ((t & 15) == 0) wcs[t >> 4] = c;
    __syncthreads();
    if (t == 0) {
        unsigned int s = 0;
        for (int i = 0; i < 16; i++) s += wcs[i];
        cnt[row] = s;
    }
}

// ---------------------------------------------------------------------------
// K2: exclusive prefix over cnt[8192] -> rowbase[8192]. One block.
// ---------------------------------------------------------------------------
__global__ __launch_bounds__(256) void k2_scan(
    const unsigned int* __restrict__ cnt, unsigned int* __restrict__ rowbase)
{
    __shared__ unsigned int ts[256];
    int t = threadIdx.x;
    unsigned int loc[32];
    unsigned int s = 0;
    const unsigned int* cp = cnt + t * 32;
    for (int i = 0; i < 32; i++) { loc[i] = s; s += cp[i]; }
    ts[t] = s;
    __syncthreads();
    unsigned int inc = s;
    for (int o = 1; o < 256; o <<= 1) {
        unsigned int u = (t >= o) ? ts[t - o] : 0u;
        __syncthreads();
        inc += u;
        ts[t] = inc;
        __syncthreads();
    }
    unsigned int base = (t == 0) ? 0u : ts[t - 1];
    unsigned int* rp = rowbase + t * 32;
    for (int i = 0; i < 32; i++) rp[i] = base + loc[i];
}

// ---------------------------------------------------------------------------
// K4: out = elu( (P_unnorm @ h) / rowsum ).  bf16 MFMA, A-frags generated
// in-register from the bitmask (no P in LDS, no barriers in K-loop).
// Block = 512 thr = 8 waves; wave wv = K-segment of 1024 cols; each wave
// owns rows m0..m0+15 x all 64 out cols (4 MFMA acc tiles).
// p_hat = exp(leaky_relu(fs[r>>13]+fd[r&8191]+ab)) unnormalized: |v|<=~6
// so exp never overflows; normalization deferred to epilogue (linear).
// ---------------------------------------------------------------------------
#define SEGW 16  // 64-bit words per segment (16*64 = 1024 cols)

__global__ __launch_bounds__(512, 4) void k4_mfma(
    const unsigned long long* __restrict__ bits,
    const unsigned int* __restrict__ rowbase,
    const unsigned int* __restrict__ cnt,
    const float* __restrict__ fs, const float* __restrict__ fd,
    const float* __restrict__ ab, const short* __restrict__ hT,
    float* __restrict__ out)
{
    __shared__ float fdl[N];           // 32 KB
    __shared__ float dred[8 * 1024];   // 32 KB: per-wave partial D tiles
    __shared__ float fsl[32];
    __shared__ float rsum[8 * 16];

    int t = threadIdx.x;
    int wv = t >> 6;          // wave id = K-segment 0..7
    int L = t & 63;
    int m = L & 15;           // A-row within tile / B-col within tile
    int g = L >> 4;           // k-octet group 0..3
    int m0 = blockIdx.x * 16;
    int row = m0 + m;

    // stage fd into LDS (8192 floats)
    for (int i = 0; i < 4; ++i) {
        int fi = i * 2048 + t * 4;
        *(float4*)&fdl[fi] = *(const float4*)&fd[fi];
    }
    unsigned int fs0 = rowbase[m0] >> 13;
    if (t < 32) {
        unsigned int idx = fs0 + (unsigned)t;
        if (idx > 8191u) idx = 8191u;
        fsl[t] = fs[idx];
    }
    __syncthreads();

    const unsigned long long* brow = bits + (size_t)row * (N / 64);
    int w0 = wv * SEGW;
    // segment start rank base for this row: rowbase + popc(words [0,w0))
    unsigned int part = 0;
    for (int w = g; w < w0; w += 4) part += (unsigned)__popcll(brow[w]);
    part += __shfl_xor(part, 16, 64);
    part += __shfl_xor(part, 32, 64);
    unsigned int base = rowbase[row] + part;

    float ab0 = ab[0];
    f32x4 acc0 = {0.f,0.f,0.f,0.f}, acc1 = {0.f,0.f,0.f,0.f};
    f32x4 acc2 = {0.f,0.f,0.f,0.f}, acc3 = {0.f,0.f,0.f,0.f};
    float psum = 0.f;
    const short* hpm = hT + (size_t)m * N;

    for (int w = w0; w < w0 + SEGW; ++w) {
        unsigned long long w64 = brow[w];
#pragma unroll
        for (int hh = 0; hh < 2; ++hh) {
            int off = hh * 32 + g * 8;
            short8 af;
#pragma unroll
            for (int j = 0; j < 8; ++j) {
                int b = off + j;
                unsigned int n = (unsigned)__popcll(w64 & ((1ull << b) - 1ull));
                unsigned int r = base + n;
                float v = fsl[(r >> 13) - fs0] + fdl[r & 8191] + ab0;
                v = v > 0.f ? v : 0.01f * v;
                float p = __expf(v);
                p = ((w64 >> b) & 1ull) ? p : 0.f;
                psum += p;
                af[j] = f2bf(p);
            }
            const short* hp = hpm + w * 64 + off;
            short8 b0 = *(const short8*)(hp);
            short8 b1 = *(const short8*)(hp + 16 * N);
            short8 b2 = *(const short8*)(hp + 32 * N);
            short8 b3 = *(const short8*)(hp + 48 * N);
            acc0 = __builtin_amdgcn_mfma_f32_16x16x32_bf16(af, b0, acc0, 0, 0, 0);
            acc1 = __builtin_amdgcn_mfma_f32_16x16x32_bf16(af, b1, acc1, 0, 0, 0);
            acc2 = __builtin_amdgcn_mfma_f32_16x16x32_bf16(af, b2, acc2, 0, 0, 0);
            acc3 = __builtin_amdgcn_mfma_f32_16x16x32_bf16(af, b3, acc3, 0, 0, 0);
        }
        base += (unsigned)__popcll(w64);
    }

    // row-sum partials: 4 g-lanes of each m hold disjoint contributions
    psum += __shfl_xor(psum, 16, 64);
    psum += __shfl_xor(psum, 32, 64);
    if (L < 16) rsum[wv * 16 + m] = psum;
    // D tile layout: col = lane&15, row = (lane>>4)*4 + reg
    float* dw = &dred[wv * 1024];
#pragma unroll
    for (int reg = 0; reg < 4; ++reg) {
        int lrow = g * 4 + reg;
        dw[lrow * 64 + m     ] = acc0[reg];
        dw[lrow * 64 + m + 16] = acc1[reg];
        dw[lrow * 64 + m + 32] = acc2[reg];
        dw[lrow * 64 + m + 48] = acc3[reg];
    }
    __syncthreads();

    // reduce 8 segments, normalize, elu, store: 1024 outputs / 512 threads
#pragma unroll
    for (int q = 0; q < 2; ++q) {
        int o = q * 512 + t;
        int lrow = o >> 6, col = o & 63;
        float s = 0.f;
#pragma unroll
        for (int v8 = 0; v8 < 8; ++v8) s += dred[v8 * 1024 + o];
        float rs = 0.f;
#pragma unroll
        for (int v8 = 0; v8 < 8; ++v8) rs += rsum[v8 * 16 + lrow];
        int grow = m0 + lrow;
        float res;
        if (cnt[grow] == 0u) {
            // empty row: softmax over all -inf = uniform 1/N (never hit in
            // practice for this input; kept for faithful semantics)
            float hs = 0.f;
            const short* hp = hT + (size_t)col * N;
            for (int j = 0; j < N; ++j) hs += bf2f(hp[j]);
            res = hs * (1.0f / 8192.0f);
        } else {
            res = s / rs;
        }
        out[(size_t)grow * NHID + col] = elu_f(res);
    }
}

// ---------------------------------------------------------------------------
extern "C" void kernel_launch(void* const* d_in, const int* in_sizes, int n_in,
                              void* d_out, int out_size, void* d_ws, size_t ws_size,
                              hipStream_t stream)
{
    const float* x   = (const float*)d_in[0];
    const int*   adj = (const int*)d_in[1];
    const float* Ww  = (const float*)d_in[2];
    const float* Wb  = (const float*)d_in[3];
    const float* a1  = (const float*)d_in[4];
    const float* a2  = (const float*)d_in[5];
    const float* ab  = (const float*)d_in[6];
    float* out = (float*)d_out;

    char* ws = (char*)d_ws;
    float* fs = (float*)(ws + 0);                          // 32 KB
    float* fd = (float*)(ws + 32768);                      // 32 KB
    unsigned int* cnt = (unsigned int*)(ws + 65536);       // 32 KB
    unsigned int* rb  = (unsigned int*)(ws + 98304);       // 32 KB
    short* hT = (short*)(ws + 131072);                     // 1 MB bf16 [64][8192]
    unsigned long long* bits = (unsigned long long*)(ws + 131072 + 1048576); // 8 MB

    k0_h_f<<<N / 4, 256, 0, stream>>>(x, Ww, Wb, a1, a2, hT, fs, fd);
    k1_bits<<<N, 256, 0, stream>>>(adj, bits, cnt);
    k2_scan<<<1, 256, 0, stream>>>(cnt, rb);
    k4_mfma<<<N / 16, 512, 0, stream>>>(bits, rb, cnt, fs, fd, ab, hT, out);
}

// Round 3
// 470.555 us; speedup vs baseline: 1.5606x; 1.0116x over previous
//
#include <hip/hip_runtime.h>
#include <hip/hip_bf16.h>

// Problem constants
#define N 8192
#define NEMB 256
#define NHID 64

typedef __attribute__((ext_vector_type(8))) short short8;   // 8 bf16 (4 VGPRs)
typedef __attribute__((ext_vector_type(4))) float f32x4;    // 4 fp32

__device__ __forceinline__ float elu_f(float x) {
    return x > 0.f ? x : __expf(x) - 1.f;
}

__device__ __forceinline__ short f2bf(float f) {
    union { float f; unsigned u; } c; c.f = f;
    unsigned r = c.u + 0x7fffu + ((c.u >> 16) & 1u);   // RNE
    return (short)(r >> 16);
}

__device__ __forceinline__ float bf2f(short s) {
    union { unsigned u; float f; } c; c.u = ((unsigned)(unsigned short)s) << 16;
    return c.f;
}

// ---------------------------------------------------------------------------
// K01: fused independent prologue work.
//  blocks [0, N):        adj row -> 64-bit mask words + per-row popcount
//  blocks [N, N+N/4):    h = x@Ww + Wb -> hT bf16 [64][8192]; fs = h@a1; fd = h@a2
// The k0-part's VALU work hides under the k1-part's HBM-bound adj read.
// ---------------------------------------------------------------------------
__global__ __launch_bounds__(256) void k01_prologue(
    const int* __restrict__ adj, unsigned long long* __restrict__ bits,
    unsigned int* __restrict__ cnt,
    const float* __restrict__ x, const float* __restrict__ Ww,
    const float* __restrict__ Wb, const float* __restrict__ a1,
    const float* __restrict__ a2, short* __restrict__ hT,
    float* __restrict__ fs, float* __restrict__ fd)
{
    int t = threadIdx.x;
    if (blockIdx.x < N) {
        // ---- k1 part: bitmask build ----
        int row = blockIdx.x;
        int lane = t & 63;
        const int* arow = adj + (size_t)row * N;
        unsigned long long* brow = bits + (size_t)row * (N / 64);
        __shared__ unsigned int wcs[16];
        unsigned int c = 0;
        for (int it = 0; it < 8; it++) {
            int j = it * 1024 + t * 4;
            int4 a = *(const int4*)&arow[j];
            unsigned int nb = (unsigned)(a.x > 0) | ((unsigned)(a.y > 0) << 1) |
                              ((unsigned)(a.z > 0) << 2) | ((unsigned)(a.w > 0) << 3);
            unsigned int v8  = nb  | (__shfl_down((int)nb, 1, 64) << 4);
            unsigned int v16 = v8  | (__shfl_down((int)v8, 2, 64) << 8);
            unsigned int v32 = v16 | (__shfl_down((int)v16, 4, 64) << 16);
            unsigned int hi  = (unsigned int)__shfl_down((int)v32, 8, 64);
            if ((lane & 15) == 0) {
                unsigned long long word = (unsigned long long)v32 |
                                          ((unsigned long long)hi << 32);
                brow[it * 16 + (t >> 4)] = word;
                c += __popcll(word);
            }
        }
        if ((t & 15) == 0) wcs[t >> 4] = c;
        __syncthreads();
        if (t == 0) {
            unsigned int s = 0;
            for (int i = 0; i < 16; i++) s += wcs[i];
            cnt[row] = s;
        }
    } else {
        // ---- k0 part: h, fs, fd ----
        __shared__ float xs[4 * NEMB];
        int rowblk = (blockIdx.x - N) * 4;
        for (int i = 0; i < 4; i++)
            xs[i * NEMB + t] = x[(size_t)rowblk * NEMB + i * NEMB + t];
        __syncthreads();
        int rl = t >> 6;     // wave id = row
        int k  = t & 63;     // lane = output column
        float acc = Wb[k];
        const float* xrow = &xs[rl * NEMB];
#pragma unroll 8
        for (int c = 0; c < NEMB; c++)
            acc = fmaf(xrow[c], Ww[c * NHID + k], acc);
        int row = rowblk + rl;
        hT[(size_t)k * N + row] = f2bf(acc);
        float s1 = acc * a1[k];
        float s2 = acc * a2[k];
        for (int o = 32; o > 0; o >>= 1) {
            s1 += __shfl_down(s1, o, 64);
            s2 += __shfl_down(s2, o, 64);
        }
        if (k == 0) { fs[row] = s1; fd[row] = s2; }
    }
}

// ---------------------------------------------------------------------------
// K2: exclusive prefix over cnt[8192] -> rowbase[8192]. One block.
// ---------------------------------------------------------------------------
__global__ __launch_bounds__(256) void k2_scan(
    const unsigned int* __restrict__ cnt, unsigned int* __restrict__ rowbase)
{
    __shared__ unsigned int ts[256];
    int t = threadIdx.x;
    unsigned int loc[32];
    unsigned int s = 0;
    const unsigned int* cp = cnt + t * 32;
#pragma unroll
    for (int i = 0; i < 32; i++) { loc[i] = s; s += cp[i]; }
    ts[t] = s;
    __syncthreads();
    unsigned int inc = s;
    for (int o = 1; o < 256; o <<= 1) {
        unsigned int u = (t >= o) ? ts[t - o] : 0u;
        __syncthreads();
        inc += u;
        ts[t] = inc;
        __syncthreads();
    }
    unsigned int base = (t == 0) ? 0u : ts[t - 1];
    unsigned int* rp = rowbase + t * 32;
#pragma unroll
    for (int i = 0; i < 32; i++) rp[i] = base + loc[i];
}

// ---------------------------------------------------------------------------
// K4: out = elu( (P_unnorm @ h) / rowsum ).  bf16 MFMA, A-frags generated
// in-register from the bitmask (no P in LDS, no barriers in K-loop).
// Block = 512 thr = 8 waves; wave wv = K-segment of 1024 cols; each wave
// owns rows m0..m0+15 x all 64 out cols (4 MFMA acc tiles).
// p_hat = exp(leaky_relu(fs[r>>13]+fd[r&8191]+ab)) unnormalized: |v|<=~6
// so exp never overflows; normalization deferred to epilogue (linear).
// Rank tracked incrementally: one popcll per 8-bit octet, then n += bit.
// ---------------------------------------------------------------------------
#define SEGW 16  // 64-bit words per segment (16*64 = 1024 cols)

__global__ __launch_bounds__(512, 4) void k4_mfma(
    const unsigned long long* __restrict__ bits,
    const unsigned int* __restrict__ rowbase,
    const unsigned int* __restrict__ cnt,
    const float* __restrict__ fs, const float* __restrict__ fd,
    const float* __restrict__ ab, const short* __restrict__ hT,
    float* __restrict__ out)
{
    __shared__ float fdl[N];           // 32 KB
    __shared__ float dred[8 * 1024];   // 32 KB: per-wave partial D tiles
    __shared__ float fsl[32];
    __shared__ float rsum[8 * 16];

    int t = threadIdx.x;
    int wv = t >> 6;          // wave id = K-segment 0..7
    int L = t & 63;
    int m = L & 15;           // A-row within tile / B-col within tile
    int g = L >> 4;           // k-octet group 0..3
    int m0 = blockIdx.x * 16;
    int row = m0 + m;

    // stage fd into LDS (8192 floats)
    for (int i = 0; i < 4; ++i) {
        int fi = i * 2048 + t * 4;
        *(float4*)&fdl[fi] = *(const float4*)&fd[fi];
    }
    unsigned int fs0 = rowbase[m0] >> 13;
    if (t < 32) {
        unsigned int idx = fs0 + (unsigned)t;
        if (idx > 8191u) idx = 8191u;
        fsl[t] = fs[idx];
    }
    __syncthreads();

    const unsigned long long* brow = bits + (size_t)row * (N / 64);
    int w0 = wv * SEGW;
    // segment start rank base for this row: rowbase + popc(words [0,w0))
    unsigned int part = 0;
    for (int w = g; w < w0; w += 4) part += (unsigned)__popcll(brow[w]);
    part += __shfl_xor(part, 16, 64);
    part += __shfl_xor(part, 32, 64);
    unsigned int base = rowbase[row] + part;

    float ab0 = ab[0];
    f32x4 acc0 = {0.f,0.f,0.f,0.f}, acc1 = {0.f,0.f,0.f,0.f};
    f32x4 acc2 = {0.f,0.f,0.f,0.f}, acc3 = {0.f,0.f,0.f,0.f};
    float psum = 0.f;
    const short* hpm = hT + (size_t)m * N;

    for (int w = w0; w < w0 + SEGW; ++w) {
        unsigned long long w64 = brow[w];
#pragma unroll
        for (int hh = 0; hh < 2; ++hh) {
            int off = hh * 32 + g * 8;
            // incremental rank within this octet
            unsigned int n = (unsigned)__popcll(w64 & ((1ull << off) - 1ull));
            unsigned int u = (unsigned int)(w64 >> off) & 0xffu;
            short8 af;
#pragma unroll
            for (int j = 0; j < 8; ++j) {
                unsigned int bit = u & 1u;
                unsigned int r = base + n;
                float v = fsl[(r >> 13) - fs0] + fdl[r & 8191] + ab0;
                v = v > 0.f ? v : 0.01f * v;
                float p = __expf(v);
                p = bit ? p : 0.f;
                psum += p;
                af[j] = f2bf(p);
                n += bit;
                u >>= 1;
            }
            const short* hp = hpm + w * 64 + off;
            short8 b0 = *(const short8*)(hp);
            short8 b1 = *(const short8*)(hp + 16 * N);
            short8 b2 = *(const short8*)(hp + 32 * N);
            short8 b3 = *(const short8*)(hp + 48 * N);
            acc0 = __builtin_amdgcn_mfma_f32_16x16x32_bf16(af, b0, acc0, 0, 0, 0);
            acc1 = __builtin_amdgcn_mfma_f32_16x16x32_bf16(af, b1, acc1, 0, 0, 0);
            acc2 = __builtin_amdgcn_mfma_f32_16x16x32_bf16(af, b2, acc2, 0, 0, 0);
            acc3 = __builtin_amdgcn_mfma_f32_16x16x32_bf16(af, b3, acc3, 0, 0, 0);
        }
        base += (unsigned)__popcll(w64);
    }

    // row-sum partials: 4 g-lanes of each m hold disjoint contributions
    psum += __shfl_xor(psum, 16, 64);
    psum += __shfl_xor(psum, 32, 64);
    if (L < 16) rsum[wv * 16 + m] = psum;
    // D tile layout: col = lane&15, row = (lane>>4)*4 + reg
    float* dw = &dred[wv * 1024];
#pragma unroll
    for (int reg = 0; reg < 4; ++reg) {
        int lrow = g * 4 + reg;
        dw[lrow * 64 + m     ] = acc0[reg];
        dw[lrow * 64 + m + 16] = acc1[reg];
        dw[lrow * 64 + m + 32] = acc2[reg];
        dw[lrow * 64 + m + 48] = acc3[reg];
    }
    __syncthreads();

    // reduce 8 segments, normalize, elu, store: 1024 outputs / 512 threads
#pragma unroll
    for (int q = 0; q < 2; ++q) {
        int o = q * 512 + t;
        int lrow = o >> 6, col = o & 63;
        float s = 0.f;
#pragma unroll
        for (int v8 = 0; v8 < 8; ++v8) s += dred[v8 * 1024 + o];
        float rs = 0.f;
#pragma unroll
        for (int v8 = 0; v8 < 8; ++v8) rs += rsum[v8 * 16 + lrow];
        int grow = m0 + lrow;
        float res;
        if (cnt[grow] == 0u) {
            // empty row: softmax over all -inf = uniform 1/N (never hit for
            // this input; kept for faithful semantics)
            float hs = 0.f;
            const short* hp = hT + (size_t)col * N;
            for (int j = 0; j < N; ++j) hs += bf2f(hp[j]);
            res = hs * (1.0f / 8192.0f);
        } else {
            res = s / rs;
        }
        out[(size_t)grow * NHID + col] = elu_f(res);
    }
}

// ---------------------------------------------------------------------------
extern "C" void kernel_launch(void* const* d_in, const int* in_sizes, int n_in,
                              void* d_out, int out_size, void* d_ws, size_t ws_size,
                              hipStream_t stream)
{
    const float* x   = (const float*)d_in[0];
    const int*   adj = (const int*)d_in[1];
    const float* Ww  = (const float*)d_in[2];
    const float* Wb  = (const float*)d_in[3];
    const float* a1  = (const float*)d_in[4];
    const float* a2  = (const float*)d_in[5];
    const float* ab  = (const float*)d_in[6];
    float* out = (float*)d_out;

    char* ws = (char*)d_ws;
    float* fs = (float*)(ws + 0);                          // 32 KB
    float* fd = (float*)(ws + 32768);                      // 32 KB
    unsigned int* cnt = (unsigned int*)(ws + 65536);       // 32 KB
    unsigned int* rb  = (unsigned int*)(ws + 98304);       // 32 KB
    short* hT = (short*)(ws + 131072);                     // 1 MB bf16 [64][8192]
    unsigned long long* bits = (unsigned long long*)(ws + 131072 + 1048576); // 8 MB

    k01_prologue<<<N + N / 4, 256, 0, stream>>>(adj, bits, cnt,
                                                x, Ww, Wb, a1, a2, hT, fs, fd);
    k2_scan<<<1, 256, 0, stream>>>(cnt, rb);
    k4_mfma<<<N / 16, 512, 0, stream>>>(bits, rb, cnt, fs, fd, ab, hT, out);
}

// Round 4
// 466.645 us; speedup vs baseline: 1.5736x; 1.0084x over previous
//
#include <hip/hip_runtime.h>
#include <hip/hip_bf16.h>

// Problem constants
#define N 8192
#define NEMB 256
#define NHID 64

typedef __attribute__((ext_vector_type(8))) short short8;   // 8 bf16 (4 VGPRs)
typedef __attribute__((ext_vector_type(4))) float f32x4;    // 4 fp32

__device__ __forceinline__ float elu_f(float x) {
    return x > 0.f ? x : __expf(x) - 1.f;
}

__device__ __forceinline__ short f2bf(float f) {
    union { float f; unsigned u; } c; c.f = f;
    unsigned r = c.u + 0x7fffu + ((c.u >> 16) & 1u);   // RNE
    return (short)(r >> 16);
}

__device__ __forceinline__ float bf2f(short s) {
    union { unsigned u; float f; } c; c.u = ((unsigned)(unsigned short)s) << 16;
    return c.f;
}

// ---------------------------------------------------------------------------
// K01: fused independent prologue work.
//  blocks [0, N):        adj row -> 64-bit mask words + per-row popcount
//  blocks [N, N+N/4):    h = x@Ww + Wb -> hT bf16 [64][8192]; fs = h@a1; fd = h@a2
// The k0-part's VALU work hides under the k1-part's HBM-bound adj read.
// ---------------------------------------------------------------------------
__global__ __launch_bounds__(256) void k01_prologue(
    const int* __restrict__ adj, unsigned long long* __restrict__ bits,
    unsigned int* __restrict__ cnt,
    const float* __restrict__ x, const float* __restrict__ Ww,
    const float* __restrict__ Wb, const float* __restrict__ a1,
    const float* __restrict__ a2, short* __restrict__ hT,
    float* __restrict__ fs, float* __restrict__ fd)
{
    int t = threadIdx.x;
    if (blockIdx.x < N) {
        // ---- k1 part: bitmask build ----
        int row = blockIdx.x;
        int lane = t & 63;
        const int* arow = adj + (size_t)row * N;
        unsigned long long* brow = bits + (size_t)row * (N / 64);
        __shared__ unsigned int wcs[16];
        unsigned int c = 0;
        for (int it = 0; it < 8; it++) {
            int j = it * 1024 + t * 4;
            int4 a = *(const int4*)&arow[j];
            unsigned int nb = (unsigned)(a.x > 0) | ((unsigned)(a.y > 0) << 1) |
                              ((unsigned)(a.z > 0) << 2) | ((unsigned)(a.w > 0) << 3);
            unsigned int v8  = nb  | (__shfl_down((int)nb, 1, 64) << 4);
            unsigned int v16 = v8  | (__shfl_down((int)v8, 2, 64) << 8);
            unsigned int v32 = v16 | (__shfl_down((int)v16, 4, 64) << 16);
            unsigned int hi  = (unsigned int)__shfl_down((int)v32, 8, 64);
            if ((lane & 15) == 0) {
                unsigned long long word = (unsigned long long)v32 |
                                          ((unsigned long long)hi << 32);
                brow[it * 16 + (t >> 4)] = word;
                c += __popcll(word);
            }
        }
        if ((t & 15) == 0) wcs[t >> 4] = c;
        __syncthreads();
        if (t == 0) {
            unsigned int s = 0;
            for (int i = 0; i < 16; i++) s += wcs[i];
            cnt[row] = s;
        }
    } else {
        // ---- k0 part: h, fs, fd ----
        __shared__ float xs[4 * NEMB];
        int rowblk = (blockIdx.x - N) * 4;
        for (int i = 0; i < 4; i++)
            xs[i * NEMB + t] = x[(size_t)rowblk * NEMB + i * NEMB + t];
        __syncthreads();
        int rl = t >> 6;     // wave id = row
        int k  = t & 63;     // lane = output column
        float acc = Wb[k];
        const float* xrow = &xs[rl * NEMB];
#pragma unroll 8
        for (int c = 0; c < NEMB; c++)
            acc = fmaf(xrow[c], Ww[c * NHID + k], acc);
        int row = rowblk + rl;
        hT[(size_t)k * N + row] = f2bf(acc);
        float s1 = acc * a1[k];
        float s2 = acc * a2[k];
        for (int o = 32; o > 0; o >>= 1) {
            s1 += __shfl_down(s1, o, 64);
            s2 += __shfl_down(s2, o, 64);
        }
        if (k == 0) { fs[row] = s1; fd[row] = s2; }
    }
}

// ---------------------------------------------------------------------------
// K4: out = elu( (P_unnorm @ h) / rowsum ).  bf16 MFMA, A-frags generated
// in-register from the bitmask (no P in LDS, no barriers in K-loop).
// Block = 512 thr = 8 waves; wave wv = K-segment of 1024 cols; each wave
// owns rows m0..m0+15 x all 64 out cols (4 MFMA acc tiles).
// p_hat = exp(leaky_relu(fs[r>>13]+fd[r&8191]+ab)) unnormalized: |v|<=~6
// so exp never overflows; normalization deferred to epilogue (linear).
// Rank tracked incrementally: one popcll per 8-bit octet, then n += bit.
// rowbase computed in-block (prefix of cnt) -- no separate scan kernel.
// ---------------------------------------------------------------------------
#define SEGW 16  // 64-bit words per segment (16*64 = 1024 cols)

__global__ __launch_bounds__(512, 4) void k4_mfma(
    const unsigned long long* __restrict__ bits,
    const unsigned int* __restrict__ cnt,
    const float* __restrict__ fs, const float* __restrict__ fd,
    const float* __restrict__ ab, const short* __restrict__ hT,
    float* __restrict__ out)
{
    __shared__ float fdl[N];             // 32 KB
    __shared__ float dred[8 * 1024];     // 32 KB: per-wave partial D tiles
    __shared__ float fsl[32];
    __shared__ float rsum[8 * 16];
    __shared__ unsigned int red512[512]; // 2 KB: rowbase reduction
    __shared__ unsigned int rb16[16];    // per-row rank bases

    int t = threadIdx.x;
    int bid = blockIdx.x;
    int wv = t >> 6;          // wave id = K-segment 0..7
    int L = t & 63;
    int m = L & 15;           // A-row within tile / B-col within tile
    int g = L >> 4;           // k-octet group 0..3
    int m0 = bid * 16;
    int row = m0 + m;

    // stage fd into LDS (8192 floats)
    for (int i = 0; i < 4; ++i) {
        int fi = i * 2048 + t * 4;
        *(float4*)&fdl[fi] = *(const float4*)&fd[fi];
    }
    // in-block rowbase: Sum cnt[0..m0). Thread t owns rows 16t..16t+15.
    unsigned int c16 = 0;
    if (t < bid) {
        const uint4* cp = (const uint4*)(cnt + t * 16);
        uint4 q0 = cp[0], q1 = cp[1], q2 = cp[2], q3 = cp[3];
        c16 = q0.x + q0.y + q0.z + q0.w + q1.x + q1.y + q1.z + q1.w +
              q2.x + q2.y + q2.z + q2.w + q3.x + q3.y + q3.z + q3.w;
    }
    red512[t] = c16;
    __syncthreads();
#pragma unroll
    for (int o = 256; o > 0; o >>= 1) {
        if (t < o) red512[t] += red512[t + o];
        __syncthreads();
    }
    unsigned int rowbase0 = red512[0];
    if (t == 0) {
        unsigned int s = rowbase0;
#pragma unroll
        for (int i = 0; i < 16; ++i) { rb16[i] = s; s += cnt[m0 + i]; }
    }
    unsigned int fs0 = rowbase0 >> 13;
    if (t < 32) {
        unsigned int idx = fs0 + (unsigned)t;
        if (idx > 8191u) idx = 8191u;
        fsl[t] = fs[idx];
    }
    __syncthreads();

    const unsigned long long* brow = bits + (size_t)row * (N / 64);
    int w0 = wv * SEGW;
    // segment start rank base for this row: rb16[m] + popc(words [0,w0))
    unsigned int part = 0;
    for (int w = g; w < w0; w += 4) part += (unsigned)__popcll(brow[w]);
    part += __shfl_xor(part, 16, 64);
    part += __shfl_xor(part, 32, 64);
    unsigned int base = rb16[m] + part;

    float ab0 = ab[0];
    f32x4 acc0 = {0.f,0.f,0.f,0.f}, acc1 = {0.f,0.f,0.f,0.f};
    f32x4 acc2 = {0.f,0.f,0.f,0.f}, acc3 = {0.f,0.f,0.f,0.f};
    float psum = 0.f;
    const short* hpm = hT + (size_t)m * N;

    for (int w = w0; w < w0 + SEGW; ++w) {
        unsigned long long w64 = brow[w];
#pragma unroll
        for (int hh = 0; hh < 2; ++hh) {
            int off = hh * 32 + g * 8;
            // incremental rank within this octet
            unsigned int n = (unsigned)__popcll(w64 & ((1ull << off) - 1ull));
            unsigned int u = (unsigned int)(w64 >> off) & 0xffu;
            short8 af;
#pragma unroll
            for (int j = 0; j < 8; ++j) {
                unsigned int bit = u & 1u;
                unsigned int r = base + n;
                float v = fsl[(r >> 13) - fs0] + fdl[r & 8191] + ab0;
                v = v > 0.f ? v : 0.01f * v;
                float p = __expf(v);
                p = bit ? p : 0.f;
                psum += p;
                af[j] = f2bf(p);
                n += bit;
                u >>= 1;
            }
            const short* hp = hpm + w * 64 + off;
            short8 b0 = *(const short8*)(hp);
            short8 b1 = *(const short8*)(hp + 16 * N);
            short8 b2 = *(const short8*)(hp + 32 * N);
            short8 b3 = *(const short8*)(hp + 48 * N);
            acc0 = __builtin_amdgcn_mfma_f32_16x16x32_bf16(af, b0, acc0, 0, 0, 0);
            acc1 = __builtin_amdgcn_mfma_f32_16x16x32_bf16(af, b1, acc1, 0, 0, 0);
            acc2 = __builtin_amdgcn_mfma_f32_16x16x32_bf16(af, b2, acc2, 0, 0, 0);
            acc3 = __builtin_amdgcn_mfma_f32_16x16x32_bf16(af, b3, acc3, 0, 0, 0);
        }
        base += (unsigned)__popcll(w64);
    }

    // row-sum partials: 4 g-lanes of each m hold disjoint contributions
    psum += __shfl_xor(psum, 16, 64);
    psum += __shfl_xor(psum, 32, 64);
    if (L < 16) rsum[wv * 16 + m] = psum;
    // D tile layout: col = lane&15, row = (lane>>4)*4 + reg
    float* dw = &dred[wv * 1024];
#pragma unroll
    for (int reg = 0; reg < 4; ++reg) {
        int lrow = g * 4 + reg;
        dw[lrow * 64 + m     ] = acc0[reg];
        dw[lrow * 64 + m + 16] = acc1[reg];
        dw[lrow * 64 + m + 32] = acc2[reg];
        dw[lrow * 64 + m + 48] = acc3[reg];
    }
    __syncthreads();

    // reduce 8 segments, normalize, elu, store: 1024 outputs / 512 threads
#pragma unroll
    for (int q = 0; q < 2; ++q) {
        int o = q * 512 + t;
        int lrow = o >> 6, col = o & 63;
        float s = 0.f;
#pragma unroll
        for (int v8 = 0; v8 < 8; ++v8) s += dred[v8 * 1024 + o];
        float rs = 0.f;
#pragma unroll
        for (int v8 = 0; v8 < 8; ++v8) rs += rsum[v8 * 16 + lrow];
        int grow = m0 + lrow;
        float res;
        if (cnt[grow] == 0u) {
            // empty row: softmax over all -inf = uniform 1/N (never hit for
            // this input; kept for faithful semantics)
            float hs = 0.f;
            const short* hp = hT + (size_t)col * N;
            for (int j = 0; j < N; ++j) hs += bf2f(hp[j]);
            res = hs * (1.0f / 8192.0f);
        } else {
            res = s / rs;
        }
        out[(size_t)grow * NHID + col] = elu_f(res);
    }
}

// ---------------------------------------------------------------------------
extern "C" void kernel_launch(void* const* d_in, const int* in_sizes, int n_in,
                              void* d_out, int out_size, void* d_ws, size_t ws_size,
                              hipStream_t stream)
{
    const float* x   = (const float*)d_in[0];
    const int*   adj = (const int*)d_in[1];
    const float* Ww  = (const float*)d_in[2];
    const float* Wb  = (const float*)d_in[3];
    const float* a1  = (const float*)d_in[4];
    const float* a2  = (const float*)d_in[5];
    const float* ab  = (const float*)d_in[6];
    float* out = (float*)d_out;

    char* ws = (char*)d_ws;
    float* fs = (float*)(ws + 0);                          // 32 KB
    float* fd = (float*)(ws + 32768);                      // 32 KB
    unsigned int* cnt = (unsigned int*)(ws + 65536);       // 32 KB
    short* hT = (short*)(ws + 98304);                      // 1 MB bf16 [64][8192]
    unsigned long long* bits = (unsigned long long*)(ws + 98304 + 1048576); // 8 MB

    k01_prologue<<<N + N / 4, 256, 0, stream>>>(adj, bits, cnt,
                                                x, Ww, Wb, a1, a2, hT, fs, fd);
    k4_mfma<<<N / 16, 512, 0, stream>>>(bits, cnt, fs, fd, ab, hT, out);
}

// Round 5
// 463.447 us; speedup vs baseline: 1.5845x; 1.0069x over previous
//
#include <hip/hip_runtime.h>
#include <hip/hip_bf16.h>

// Problem constants
#define N 8192
#define NEMB 256
#define NHID 64
#define LOG2E 1.4426950408889634f

typedef __attribute__((ext_vector_type(8))) short short8;   // 8 bf16 (4 VGPRs)
typedef __attribute__((ext_vector_type(4))) float f32x4;    // 4 fp32

__device__ __forceinline__ float elu_f(float x) {
    return x > 0.f ? x : __expf(x) - 1.f;
}

__device__ __forceinline__ float exp2_fast(float x) {
#if __has_builtin(__builtin_amdgcn_exp2f)
    return __builtin_amdgcn_exp2f(x);
#else
    return exp2f(x);
#endif
}

__device__ __forceinline__ short f2bf(float f) {
    union { float f; unsigned u; } c; c.f = f;
    unsigned r = c.u + 0x7fffu + ((c.u >> 16) & 1u);   // RNE
    return (short)(r >> 16);
}

__device__ __forceinline__ float bf2f(short s) {
    union { unsigned u; float f; } c; c.u = ((unsigned)(unsigned short)s) << 16;
    return c.f;
}

// ---------------------------------------------------------------------------
// K01: fused independent prologue work.
//  blocks [0, N):        adj row -> 64-bit mask words + per-row popcount
//  blocks [N, N+N/4):    h = x@Ww + Wb -> hT bf16 [64][8192]; fs = h@a1; fd = h@a2
// ---------------------------------------------------------------------------
__global__ __launch_bounds__(256) void k01_prologue(
    const int* __restrict__ adj, unsigned long long* __restrict__ bits,
    unsigned int* __restrict__ cnt,
    const float* __restrict__ x, const float* __restrict__ Ww,
    const float* __restrict__ Wb, const float* __restrict__ a1,
    const float* __restrict__ a2, short* __restrict__ hT,
    float* __restrict__ fs, float* __restrict__ fd)
{
    int t = threadIdx.x;
    if (blockIdx.x < N) {
        // ---- k1 part: bitmask build ----
        int row = blockIdx.x;
        int lane = t & 63;
        const int* arow = adj + (size_t)row * N;
        unsigned long long* brow = bits + (size_t)row * (N / 64);
        __shared__ unsigned int wcs[16];
        unsigned int c = 0;
        for (int it = 0; it < 8; it++) {
            int j = it * 1024 + t * 4;
            int4 a = *(const int4*)&arow[j];
            unsigned int nb = (unsigned)(a.x > 0) | ((unsigned)(a.y > 0) << 1) |
                              ((unsigned)(a.z > 0) << 2) | ((unsigned)(a.w > 0) << 3);
            unsigned int v8  = nb  | (__shfl_down((int)nb, 1, 64) << 4);
            unsigned int v16 = v8  | (__shfl_down((int)v8, 2, 64) << 8);
            unsigned int v32 = v16 | (__shfl_down((int)v16, 4, 64) << 16);
            unsigned int hi  = (unsigned int)__shfl_down((int)v32, 8, 64);
            if ((lane & 15) == 0) {
                unsigned long long word = (unsigned long long)v32 |
                                          ((unsigned long long)hi << 32);
                brow[it * 16 + (t >> 4)] = word;
                c += __popcll(word);
            }
        }
        if ((t & 15) == 0) wcs[t >> 4] = c;
        __syncthreads();
        if (t == 0) {
            unsigned int s = 0;
            for (int i = 0; i < 16; i++) s += wcs[i];
            cnt[row] = s;
        }
    } else {
        // ---- k0 part: h, fs, fd ----
        __shared__ float xs[4 * NEMB];
        int rowblk = (blockIdx.x - N) * 4;
        for (int i = 0; i < 4; i++)
            xs[i * NEMB + t] = x[(size_t)rowblk * NEMB + i * NEMB + t];
        __syncthreads();
        int rl = t >> 6;     // wave id = row
        int k  = t & 63;     // lane = output column
        float acc = Wb[k];
        const float* xrow = &xs[rl * NEMB];
#pragma unroll 8
        for (int c = 0; c < NEMB; c++)
            acc = fmaf(xrow[c], Ww[c * NHID + k], acc);
        int row = rowblk + rl;
        hT[(size_t)k * N + row] = f2bf(acc);
        float s1 = acc * a1[k];
        float s2 = acc * a2[k];
        for (int o = 32; o > 0; o >>= 1) {
            s1 += __shfl_down(s1, o, 64);
            s2 += __shfl_down(s2, o, 64);
        }
        if (k == 0) { fs[row] = s1; fd[row] = s2; }
    }
}

// ---------------------------------------------------------------------------
// K4: out = elu( (P_unnorm @ h) / rowsum ).  bf16 MFMA, A-frags generated
// in-register from the bitmask.  p_hat = exp(lrelu(fs_i+fd_j+ab)),
// computed as exp2(lrelu(s' + d')) with log2e folded into the staged tables
// (lrelu is positively homogeneous).  Per-bit fs lookup replaced by a
// cmp/cndmask against the (single possible) 8192-rank window crossing R*.
// bf16 pack via +0x8000 round + v_perm_b32 pair pack.
// ---------------------------------------------------------------------------
#define SEGW 16  // 64-bit words per segment (16*64 = 1024 cols)

__global__ __launch_bounds__(512, 4) void k4_mfma(
    const unsigned long long* __restrict__ bits,
    const unsigned int* __restrict__ cnt,
    const float* __restrict__ fs, const float* __restrict__ fd,
    const float* __restrict__ ab, const short* __restrict__ hT,
    float* __restrict__ out)
{
    __shared__ float fdl[N];             // 32 KB (fd * log2e)
    __shared__ float dred[8 * 1024];     // 32 KB: per-wave partial D tiles
    __shared__ float fsl[32];            // (fs + ab) * log2e window
    __shared__ float rsum[8 * 16];
    __shared__ unsigned int red512[512]; // 2 KB: rowbase reduction
    __shared__ unsigned int rb16[16];    // per-row rank bases

    int t = threadIdx.x;
    int bid = blockIdx.x;
    int wv = t >> 6;          // wave id = K-segment 0..7
    int L = t & 63;
    int m = L & 15;           // A-row within tile / B-col within tile
    int g = L >> 4;           // k-octet group 0..3
    int m0 = bid * 16;
    int row = m0 + m;
    float ab0 = ab[0];

    // stage fd*log2e into LDS (8192 floats)
    for (int i = 0; i < 4; ++i) {
        int fi = i * 2048 + t * 4;
        float4 v4 = *(const float4*)&fd[fi];
        v4.x *= LOG2E; v4.y *= LOG2E; v4.z *= LOG2E; v4.w *= LOG2E;
        *(float4*)&fdl[fi] = v4;
    }
    // in-block rowbase: Sum cnt[0..m0). Thread t owns rows 16t..16t+15.
    unsigned int c16 = 0;
    if (t < bid) {
        const uint4* cp = (const uint4*)(cnt + t * 16);
        uint4 q0 = cp[0], q1 = cp[1], q2 = cp[2], q3 = cp[3];
        c16 = q0.x + q0.y + q0.z + q0.w + q1.x + q1.y + q1.z + q1.w +
              q2.x + q2.y + q2.z + q2.w + q3.x + q3.y + q3.z + q3.w;
    }
    red512[t] = c16;
    __syncthreads();
#pragma unroll
    for (int o = 256; o > 0; o >>= 1) {
        if (t < o) red512[t] += red512[t + o];
        __syncthreads();
    }
    unsigned int rowbase0 = red512[0];
    if (t == 0) {
        unsigned int s = rowbase0;
#pragma unroll
        for (int i = 0; i < 16; ++i) { rb16[i] = s; s += cnt[m0 + i]; }
    }
    unsigned int fs0 = rowbase0 >> 13;
    if (t < 32) {
        unsigned int idx = fs0 + (unsigned)t;
        if (idx > 8191u) idx = 8191u;
        fsl[t] = (fs[idx] + ab0) * LOG2E;
    }
    __syncthreads();

    // per-row fs window: row spans <= 8192 ranks -> at most one crossing
    unsigned int rbm = rb16[m];
    unsigned int w13 = rbm >> 13;
    float s0 = fsl[w13 - fs0];
    unsigned int i1 = w13 + 1 - fs0; if (i1 > 31u) i1 = 31u;
    float s1 = fsl[i1];
    unsigned int Rstar = (w13 + 1u) << 13;   // first rank using s1

    const unsigned long long* brow = bits + (size_t)row * (N / 64);
    int w0 = wv * SEGW;
    // segment start rank base for this row: rbm + popc(words [0,w0))
    unsigned int part = 0;
    for (int w = g; w < w0; w += 4) part += (unsigned)__popcll(brow[w]);
    part += __shfl_xor(part, 16, 64);
    part += __shfl_xor(part, 32, 64);
    unsigned int base = rbm + part;

    f32x4 acc0 = {0.f,0.f,0.f,0.f}, acc1 = {0.f,0.f,0.f,0.f};
    f32x4 acc2 = {0.f,0.f,0.f,0.f}, acc3 = {0.f,0.f,0.f,0.f};
    float psum = 0.f;
    const short* hpm = hT + (size_t)m * N;

    for (int w = w0; w < w0 + SEGW; ++w) {
        unsigned long long w64 = brow[w];
#pragma unroll
        for (int hh = 0; hh < 2; ++hh) {
            int off = hh * 32 + g * 8;
            unsigned int n = (unsigned)__popcll(w64 & ((1ull << off) - 1ull));
            unsigned int u = (unsigned int)(w64 >> off) & 0xffu;
            unsigned int pu[8];
#pragma unroll
            for (int j = 0; j < 8; ++j) {
                unsigned int bit = (u >> j) & 1u;
                unsigned int r = base + n;
                float d = fdl[r & 8191u];
                float sv = (r >= Rstar) ? s1 : s0;
                float v = sv + d;
                float lr = fmaxf(v, 0.01f * v);     // leaky_relu (both signs)
                float p = exp2_fast(lr);
                p = bit ? p : 0.f;
                psum += p;
                union { float f; unsigned u; } cv; cv.f = p;
                pu[j] = cv.u + 0x8000u;             // round-half-up to bf16
                n += bit;
            }
            union { short8 v; unsigned q[4]; } afu;
#pragma unroll
            for (int k = 0; k < 4; ++k)
                afu.q[k] = __builtin_amdgcn_perm(pu[2 * k + 1], pu[2 * k],
                                                 0x07060302u);
            const short* hp = hpm + w * 64 + off;
            short8 b0 = *(const short8*)(hp);
            short8 b1 = *(const short8*)(hp + 16 * N);
            short8 b2 = *(const short8*)(hp + 32 * N);
            short8 b3 = *(const short8*)(hp + 48 * N);
            acc0 = __builtin_amdgcn_mfma_f32_16x16x32_bf16(afu.v, b0, acc0, 0, 0, 0);
            acc1 = __builtin_amdgcn_mfma_f32_16x16x32_bf16(afu.v, b1, acc1, 0, 0, 0);
            acc2 = __builtin_amdgcn_mfma_f32_16x16x32_bf16(afu.v, b2, acc2, 0, 0, 0);
            acc3 = __builtin_amdgcn_mfma_f32_16x16x32_bf16(afu.v, b3, acc3, 0, 0, 0);
        }
        base += (unsigned)__popcll(w64);
    }

    // row-sum partials: 4 g-lanes of each m hold disjoint contributions
    psum += __shfl_xor(psum, 16, 64);
    psum += __shfl_xor(psum, 32, 64);
    if (L < 16) rsum[wv * 16 + m] = psum;
    // D tile layout: col = lane&15, row = (lane>>4)*4 + reg
    float* dw = &dred[wv * 1024];
#pragma unroll
    for (int reg = 0; reg < 4; ++reg) {
        int lrow = g * 4 + reg;
        dw[lrow * 64 + m     ] = acc0[reg];
        dw[lrow * 64 + m + 16] = acc1[reg];
        dw[lrow * 64 + m + 32] = acc2[reg];
        dw[lrow * 64 + m + 48] = acc3[reg];
    }
    __syncthreads();

    // reduce 8 segments, normalize, elu, store: 1024 outputs / 512 threads
#pragma unroll
    for (int q = 0; q < 2; ++q) {
        int o = q * 512 + t;
        int lrow = o >> 6, col = o & 63;
        float s = 0.f;
#pragma unroll
        for (int v8 = 0; v8 < 8; ++v8) s += dred[v8 * 1024 + o];
        float rs = 0.f;
#pragma unroll
        for (int v8 = 0; v8 < 8; ++v8) rs += rsum[v8 * 16 + lrow];
        int grow = m0 + lrow;
        float res;
        if (cnt[grow] == 0u) {
            // empty row: softmax over all -inf = uniform 1/N (never hit for
            // this input; kept for faithful semantics)
            float hs = 0.f;
            const short* hp = hT + (size_t)col * N;
            for (int j = 0; j < N; ++j) hs += bf2f(hp[j]);
            res = hs * (1.0f / 8192.0f);
        } else {
            res = s / rs;
        }
        out[(size_t)grow * NHID + col] = elu_f(res);
    }
}

// ---------------------------------------------------------------------------
extern "C" void kernel_launch(void* const* d_in, const int* in_sizes, int n_in,
                              void* d_out, int out_size, void* d_ws, size_t ws_size,
                              hipStream_t stream)
{
    const float* x   = (const float*)d_in[0];
    const int*   adj = (const int*)d_in[1];
    const float* Ww  = (const float*)d_in[2];
    const float* Wb  = (const float*)d_in[3];
    const float* a1  = (const float*)d_in[4];
    const float* a2  = (const float*)d_in[5];
    const float* ab  = (const float*)d_in[6];
    float* out = (float*)d_out;

    char* ws = (char*)d_ws;
    float* fs = (float*)(ws + 0);                          // 32 KB
    float* fd = (float*)(ws + 32768);                      // 32 KB
    unsigned int* cnt = (unsigned int*)(ws + 65536);       // 32 KB
    short* hT = (short*)(ws + 98304);                      // 1 MB bf16 [64][8192]
    unsigned long long* bits = (unsigned long long*)(ws + 98304 + 1048576); // 8 MB

    k01_prologue<<<N + N / 4, 256, 0, stream>>>(adj, bits, cnt,
                                                x, Ww, Wb, a1, a2, hT, fs, fd);
    k4_mfma<<<N / 16, 512, 0, stream>>>(bits, cnt, fs, fd, ab, hT, out);
}